// Round 1
// baseline (3613.165 us; speedup 1.0000x reference)
//
#include <hip/hip_runtime.h>

constexpr int NN  = 50000;
constexpr int NE  = 800000;
constexpr int NEN = NE + NN;          // edges + self-loops
constexpr int FIN = 1433;
constexpr int H   = 8;
constexpr int NC  = 7;
constexpr int PH  = 16;
constexpr int L   = 3;
constexpr int D0  = 56;               // H*NC
constexpr int DH  = 128;              // PH*H

// ---------------- CSR construction ----------------

__global__ void k_count(const int* __restrict__ ei, int* __restrict__ deg) {
    int e = blockIdx.x * blockDim.x + threadIdx.x;
    if (e >= NEN) return;
    int d = (e < NE) ? ei[NE + e] : (e - NE);
    atomicAdd(&deg[d], 1);
}

__global__ void k_dinv(const int* __restrict__ deg, float* __restrict__ dinv) {
    int n = blockIdx.x * blockDim.x + threadIdx.x;
    if (n >= NN) return;
    dinv[n] = rsqrtf(fmaxf((float)deg[n], 1.0f));
}

__global__ void k_scan(const int* __restrict__ deg, int* __restrict__ rp, int* __restrict__ cur) {
    __shared__ int part[256];
    __shared__ int pref[257];
    int tid = threadIdx.x;
    const int chunk = (NN + 255) / 256;
    int lo = tid * chunk, hi = min(lo + chunk, NN);
    int s = 0;
    for (int i = lo; i < hi; i++) s += deg[i];
    part[tid] = s;
    __syncthreads();
    if (tid == 0) {
        int acc = 0;
        for (int i = 0; i < 256; i++) { pref[i] = acc; acc += part[i]; }
        pref[256] = acc;
    }
    __syncthreads();
    int run = pref[tid];
    for (int i = lo; i < hi; i++) { rp[i] = run; cur[i] = run; run += deg[i]; }
    if (tid == 0) rp[NN] = pref[256];
}

__global__ void k_fill(const int* __restrict__ ei, const float* __restrict__ dinv,
                       int* __restrict__ cur, int* __restrict__ csrc, float* __restrict__ cnrm) {
    int e = blockIdx.x * blockDim.x + threadIdx.x;
    if (e >= NEN) return;
    int s, d;
    if (e < NE) { s = ei[e]; d = ei[NE + e]; } else { s = d = e - NE; }
    int pos = atomicAdd(&cur[d], 1);
    csrc[pos] = s;
    cnrm[pos] = dinv[s] * dinv[d];
}

// ---------------- generic fp32 GEMM: C[M,Dout] = A[M,K] @ B[K,Dout] (+bias)(+relu) ----------------

template <int DP>   // padded Dout: 64 or 128
__global__ __launch_bounds__(256) void k_gemm(const float* __restrict__ A, int M, int K,
                                              const float* __restrict__ B, int Dout,
                                              const float* __restrict__ bias,
                                              float* __restrict__ Cc, int do_relu) {
    constexpr int KT = 16;
    constexpr int CG = DP / 4;        // col groups (float4 per thread)
    constexpr int RT = 256 / CG;      // row-threads
    constexpr int NR = 64 / RT;       // rows per thread
    __shared__ float As[64][KT + 1];
    __shared__ float Bs[KT][DP];
    int tid = threadIdx.x;
    int cg = tid % CG, rt = tid / CG;
    int r0 = blockIdx.x * 64;
    float acc[NR][4];
#pragma unroll
    for (int j = 0; j < NR; j++)
#pragma unroll
        for (int q = 0; q < 4; q++) acc[j][q] = 0.f;

    for (int k0 = 0; k0 < K; k0 += KT) {
#pragma unroll
        for (int i = 0; i < 4; i++) {
            int idx = tid + 256 * i;          // 1024 = 64x16 elements
            int r = idx >> 4, kk = idx & 15;
            int gr = r0 + r, gk = k0 + kk;
            As[r][kk] = (gr < M && gk < K) ? A[(long)gr * K + gk] : 0.f;
        }
        for (int idx = tid; idx < KT * DP; idx += 256) {
            int k = idx / DP, c = idx % DP;
            int gk = k0 + k;
            Bs[k][c] = (gk < K && c < Dout) ? B[gk * Dout + c] : 0.f;
        }
        __syncthreads();
#pragma unroll
        for (int kk = 0; kk < KT; kk++) {
            float4 b4 = *reinterpret_cast<const float4*>(&Bs[kk][cg * 4]);
#pragma unroll
            for (int j = 0; j < NR; j++) {
                float a = As[rt + j * RT][kk];
                acc[j][0] += a * b4.x; acc[j][1] += a * b4.y;
                acc[j][2] += a * b4.z; acc[j][3] += a * b4.w;
            }
        }
        __syncthreads();
    }
#pragma unroll
    for (int j = 0; j < NR; j++) {
        int r = r0 + rt + j * RT;
        if (r >= M) continue;
#pragma unroll
        for (int q = 0; q < 4; q++) {
            int c = cg * 4 + q;
            if (c < Dout) {
                float v = acc[j][q] + (bias ? bias[c] : 0.f);
                if (do_relu) v = fmaxf(v, 0.f);
                Cc[(long)r * Dout + c] = v;
            }
        }
    }
}

// ---------------- GCN aggregation: out[n,:] = relu(sum_e norm*t[src,:] + b) ----------------

template <int TPN, int NPB>   // threads per node, nodes per block (TPN*NPB==256)
__global__ __launch_bounds__(256) void k_gcn_agg(const float* __restrict__ t, int Dout,
                                                 const int* __restrict__ rp, const int* __restrict__ csrc,
                                                 const float* __restrict__ cnrm, const float* __restrict__ bias,
                                                 float* __restrict__ out, int do_relu) {
    int tid = threadIdx.x;
    int c4 = tid % TPN, ln = tid / TPN;
    int n = blockIdx.x * NPB + ln;
    if (n >= NN) return;
    int cols = c4 * 4;
    bool valid = cols < Dout;
    float4 acc = {0.f, 0.f, 0.f, 0.f};
    int e0 = rp[n], e1 = rp[n + 1];
    for (int e = e0; e < e1; e++) {
        int s = csrc[e];
        float w = cnrm[e];
        if (valid) {
            float4 v = *reinterpret_cast<const float4*>(&t[(long)s * Dout + cols]);
            acc.x += w * v.x; acc.y += w * v.y; acc.z += w * v.z; acc.w += w * v.w;
        }
    }
    if (valid) {
        float4 b4 = *reinterpret_cast<const float4*>(&bias[cols]);
        acc.x += b4.x; acc.y += b4.y; acc.z += b4.z; acc.w += b4.w;
        if (do_relu) {
            acc.x = fmaxf(acc.x, 0.f); acc.y = fmaxf(acc.y, 0.f);
            acc.z = fmaxf(acc.z, 0.f); acc.w = fmaxf(acc.w, 0.f);
        }
        *reinterpret_cast<float4*>(&out[(long)n * Dout + cols]) = acc;
    }
}

// ---------------- GAT ----------------

__global__ void k_gat_scores(const float* __restrict__ hh, const float* __restrict__ a_s,
                             const float* __restrict__ a_d, float* __restrict__ es, float* __restrict__ ed) {
    int tid = blockIdx.x * blockDim.x + threadIdx.x;
    int n = tid >> 3, h = tid & 7;
    if (n >= NN) return;
    const float* row = hh + (long)n * DH + h * PH;
    const float* vs = a_s + h * PH;
    const float* vd = a_d + h * PH;
    float s = 0.f, d = 0.f;
#pragma unroll
    for (int p = 0; p < PH; p++) { float v = row[p]; s += v * vs[p]; d += v * vd[p]; }
    es[n * 8 + h] = s;
    ed[n * 8 + h] = d;
}

__global__ void k_gat_prep(const float* __restrict__ es, const float* __restrict__ ed,
                           const int* __restrict__ rp, const int* __restrict__ csrc,
                           float* __restrict__ emax, float* __restrict__ rden) {
    int tid = blockIdx.x * blockDim.x + threadIdx.x;
    int n = tid >> 3, h = tid & 7;
    if (n >= NN) return;
    int e0 = rp[n], e1 = rp[n + 1];
    float edn = ed[n * 8 + h];
    float m = -1e30f;
    for (int e = e0; e < e1; e++) {
        float v = es[csrc[e] * 8 + h] + edn;
        v = (v > 0.f) ? v : 0.2f * v;
        m = fmaxf(m, v);
    }
    float den = 0.f;
    for (int e = e0; e < e1; e++) {
        float v = es[csrc[e] * 8 + h] + edn;
        v = (v > 0.f) ? v : 0.2f * v;
        den += __expf(v - m);
    }
    emax[n * 8 + h] = m;
    rden[n * 8 + h] = 1.0f / den;
}

__global__ __launch_bounds__(256) void k_gat_agg(const float* __restrict__ hh, const float* __restrict__ es,
                                                 const float* __restrict__ ed, const float* __restrict__ emax,
                                                 const float* __restrict__ rden,
                                                 const int* __restrict__ rp, const int* __restrict__ csrc,
                                                 const float* __restrict__ bias, float* __restrict__ out16) {
    int tid = threadIdx.x;
    int p4 = tid & 3, h = (tid >> 2) & 7, ln = tid >> 5;   // 8 nodes/block, 32 threads/node
    int n = blockIdx.x * 8 + ln;
    if (n >= NN) return;
    int e0 = rp[n], e1 = rp[n + 1];
    float edn = ed[n * 8 + h];
    float mx = emax[n * 8 + h];
    float rd = rden[n * 8 + h];
    float4 acc = {0.f, 0.f, 0.f, 0.f};
    for (int e = e0; e < e1; e++) {
        int s = csrc[e];
        float v = es[s * 8 + h] + edn;
        v = (v > 0.f) ? v : 0.2f * v;
        float w = __expf(v - mx);
        float4 hv = *reinterpret_cast<const float4*>(&hh[(long)s * DH + h * PH + p4 * 4]);
        acc.x += w * hv.x; acc.y += w * hv.y; acc.z += w * hv.z; acc.w += w * hv.w;
    }
    acc.x *= rd; acc.y *= rd; acc.z *= rd; acc.w *= rd;
    // reduce over h: lanes h*4+p4 within each 32-lane group
#pragma unroll
    for (int msk = 4; msk <= 16; msk <<= 1) {
        acc.x += __shfl_xor(acc.x, msk, 64);
        acc.y += __shfl_xor(acc.y, msk, 64);
        acc.z += __shfl_xor(acc.z, msk, 64);
        acc.w += __shfl_xor(acc.w, msk, 64);
    }
    if (h == 0) {
        int c = p4 * 4;
        float4 b4 = *reinterpret_cast<const float4*>(&bias[c]);
        float4 o;
        o.x = acc.x * 0.125f + b4.x;
        o.y = acc.y * 0.125f + b4.y;
        o.z = acc.z * 0.125f + b4.z;
        o.w = acc.w * 0.125f + b4.w;
        *reinterpret_cast<float4*>(&out16[(long)n * PH + c]) = o;
    }
}

// ---------------- driver ----------------

extern "C" void kernel_launch(void* const* d_in, const int* in_sizes, int n_in,
                              void* d_out, int out_size, void* d_ws, size_t ws_size,
                              hipStream_t stream) {
    const float* x      = (const float*)d_in[0];
    const int*   ei     = (const int*)  d_in[1];
    const float* w_feat = (const float*)d_in[2];
    const float* b_feat = (const float*)d_in[3];
    const float* gcn0_w = (const float*)d_in[4];
    const float* gcn0_b = (const float*)d_in[5];
    const float* gcn_w  = (const float*)d_in[6];
    const float* gcn_b  = (const float*)d_in[7];
    const float* gat_w  = (const float*)d_in[8];
    const float* gat_as = (const float*)d_in[9];
    const float* gat_ad = (const float*)d_in[10];
    const float* gat_bb = (const float*)d_in[11];
    const float* mas_w  = (const float*)d_in[12];
    const float* mas_b  = (const float*)d_in[13];
    const float* out_w  = (const float*)d_in[14];
    const float* out_b  = (const float*)d_in[15];
    float* out = (float*)d_out;

    char* ws = (char*)d_ws;
    size_t off = 0;
    auto alloc = [&](size_t bytes) { void* p = ws + off; off = (off + bytes + 255) & ~(size_t)255; return p; };
    int*   deg  = (int*)  alloc((size_t)NN * 4);
    float* dinv = (float*)alloc((size_t)NN * 4);
    int*   rp   = (int*)  alloc((size_t)(NN + 1) * 4);
    int*   cur  = (int*)  alloc((size_t)NN * 4);
    int*   csrc = (int*)  alloc((size_t)NEN * 4);
    float* cnrm = (float*)alloc((size_t)NEN * 4);
    float* es   = (float*)alloc((size_t)NN * 8 * 4);
    float* ed   = (float*)alloc((size_t)NN * 8 * 4);
    float* emax = (float*)alloc((size_t)NN * 8 * 4);
    float* rden = (float*)alloc((size_t)NN * 8 * 4);
    float* bufH = (float*)alloc((size_t)NN * 64 * 4);
    float* bufG = (float*)alloc((size_t)NN * DH * 4);
    float* bufT = (float*)alloc((size_t)NN * DH * 4);
    (void)ws_size; (void)in_sizes; (void)n_in; (void)out_size;

    hipMemsetAsync(deg, 0, (size_t)NN * 4, stream);
    k_count<<<(NEN + 255) / 256, 256, 0, stream>>>(ei, deg);
    k_dinv<<<(NN + 255) / 256, 256, 0, stream>>>(deg, dinv);
    k_scan<<<1, 256, 0, stream>>>(deg, rp, cur);
    k_fill<<<(NEN + 255) / 256, 256, 0, stream>>>(ei, dinv, cur, csrc, cnrm);

    const int GB = (NN + 63) / 64;

    // GNFE: relu(gcn(x, w_feat, b_feat))
    k_gemm<64><<<GB, 256, 0, stream>>>(x, NN, FIN, w_feat, D0, nullptr, bufT, 0);
    k_gcn_agg<16, 16><<<NN / 16, 256, 0, stream>>>(bufT, D0, rp, csrc, cnrm, b_feat, bufH, 1);

    for (int m = 0; m < L; m++) {
        for (int i = 0; i < L; i++) {
            const float* Wg = (i == 0) ? gcn0_w + (size_t)m * D0 * DH
                                       : gcn_w + (size_t)(m * (L - 1) + (i - 1)) * PH * DH;
            const float* bg = (i == 0) ? gcn0_b + m * DH
                                       : gcn_b + (m * (L - 1) + (i - 1)) * DH;
            const float* A  = (i == 0) ? bufH : bufG;
            int K = (i == 0) ? D0 : PH;
            // GCN: gemm -> aggregate(+bias,+relu)
            k_gemm<128><<<GB, 256, 0, stream>>>(A, NN, K, Wg, DH, nullptr, bufT, 0);
            k_gcn_agg<32, 8><<<NN / 8, 256, 0, stream>>>(bufT, DH, rp, csrc, cnrm, bg, bufG, 1);
            // GAT
            int li = m * L + i;
            k_gemm<128><<<GB, 256, 0, stream>>>(bufG, NN, DH, gat_w + (size_t)li * DH * DH, DH, nullptr, bufT, 0);
            k_gat_scores<<<(NN * 8 + 255) / 256, 256, 0, stream>>>(bufT, gat_as + li * H * PH, gat_ad + li * H * PH, es, ed);
            k_gat_prep<<<(NN * 8 + 255) / 256, 256, 0, stream>>>(es, ed, rp, csrc, emax, rden);
            k_gat_agg<<<NN / 8, 256, 0, stream>>>(bufT, es, ed, emax, rden, rp, csrc, gat_bb + li * PH, bufG);
        }
        // MAS: h = h @ mas_w[m] + mas_b[m]
        k_gemm<64><<<GB, 256, 0, stream>>>(bufG, NN, PH, mas_w + (size_t)m * PH * D0, D0, mas_b + m * D0, bufH, 0);
    }
    // output projection
    k_gemm<64><<<GB, 256, 0, stream>>>(bufH, NN, D0, out_w, NC, out_b, out, 0);
}